// Round 19
// baseline (145.060 us; speedup 1.0000x reference)
//
#include <hip/hip_runtime.h>

// Problem: B=4, T=2048, C=1024, H=16, D=64.  x:[B,T,C] f32, w:[C,3C] f32.
// Plan: fused prep (x->bf16, w->w^T bf16) ; m97-style MFMA GEMM -> qkv ;
//       flash attention (causal, fixed-max softmax) -> out f32 [B,T,C].
// R11: swapped QK^T -> S^T, b64 P staging. R12: per-CU extent map + fused prep.
// R15: double P buffer. R16: compiler-cvt P pack. R17: MFMA rowsum.
// R18: exp2-folded Q scale + raw v_exp_f32 (VALU 31.9->27.4).
// R19: (a) gemm epilogue f2bf -> f2bf_cvt (192 VALU ops -> 32 cvt_pk in the
//      serial tail); (b) attn V-pack via v_perm_b32 (1 op vs shl+or, -8/iter).

#define B_ 4
#define T_ 2048
#define C_ 1024
#define H_ 16
#define D_ 64
#define QKV1 (B_*H_*T_*D_)   // 8,388,608 elements per q/k/v

typedef __attribute__((ext_vector_type(4))) float  f32x4;
typedef __attribute__((ext_vector_type(8))) short  bf16x8;
typedef __attribute__((ext_vector_type(4))) short  bf16x4;

__device__ inline unsigned short f2bf(float f) {
  unsigned int u = __builtin_bit_cast(unsigned int, f);
  u += 0x7FFFu + ((u >> 16) & 1u);          // RNE
  return (unsigned short)(u >> 16);
}

// compiler-visible f32->bf16 cast: lowers to v_cvt_pk_bf16_f32 when paired
__device__ inline unsigned short f2bf_cvt(float f) {
  __bf16 h = (__bf16)f;
  return __builtin_bit_cast(unsigned short, h);
}

__device__ inline void gload16(const unsigned short* g, unsigned short* l) {
  __builtin_amdgcn_global_load_lds(
      (const __attribute__((address_space(1))) void*)g,
      (__attribute__((address_space(3))) void*)l, 16, 0, 0);
}

// ---------------- fused prep: x->bf16 (blocks 0..2047), w->w^T bf16 (2048..5119) ----
__global__ __launch_bounds__(256) void prep(const float* __restrict__ x,
                                            unsigned short* __restrict__ xb,
                                            const float* __restrict__ w,
                                            unsigned short* __restrict__ wt) {
  if (blockIdx.x < 2048) {
    size_t i = ((size_t)blockIdx.x * 256 + threadIdx.x) * 16;
    f32x4 a = *(const f32x4*)(x + i);
    f32x4 b = *(const f32x4*)(x + i + 4);
    f32x4 c = *(const f32x4*)(x + i + 8);
    f32x4 d = *(const f32x4*)(x + i + 12);
    bf16x8 o0, o1;
#pragma unroll
    for (int j = 0; j < 4; j++) {
      o0[j]     = (short)f2bf(a[j]);
      o0[j + 4] = (short)f2bf(b[j]);
      o1[j]     = (short)f2bf(c[j]);
      o1[j + 4] = (short)f2bf(d[j]);
    }
    *(bf16x8*)(xb + i) = o0;
    *(bf16x8*)(xb + i + 8) = o1;
  } else {
    __shared__ float tile[32][33];
    const int bid = blockIdx.x - 2048;
    const int tx = threadIdx.x & 31, ty = threadIdx.x >> 5;   // 32 x 8
    const int n0 = (bid % 96) * 32, k0 = (bid / 96) * 32;
#pragma unroll
    for (int j = 0; j < 4; j++) {
      int k = ty + j * 8;
      tile[k][tx] = w[(size_t)(k0 + k) * 3072 + n0 + tx];
    }
    __syncthreads();
#pragma unroll
    for (int j = 0; j < 4; j++) {
      int n = ty + j * 8;
      wt[(size_t)(n0 + n) * 1024 + k0 + tx] = f2bf(tile[tx][n]);
    }
  }
}

// ---------------- QKV GEMM: [8192,1024]bf16 x [1024,3072]bf16 -> bf16 qkv ----------------
// BM=BN=128, BK=64, 256 threads (4 waves 2x2, wave tile 64x64), 16x16x32 MFMA.
__global__ __launch_bounds__(256) void qkv_gemm(const unsigned short* __restrict__ xb,
                                                const unsigned short* __restrict__ wt,
                                                unsigned short* __restrict__ qkv) {
  __shared__ unsigned short Al[128 * 64];   // 16 KB
  __shared__ unsigned short Bl[128 * 64];   // 16 KB
  const int tid = threadIdx.x;
  const int lane = tid & 63, wid = tid >> 6;
  const int l15 = lane & 15, g = lane >> 4;
  const int m0 = blockIdx.y * 128, n0 = blockIdx.x * 128;
  const int wm = (wid >> 1) * 64, wn = (wid & 1) * 64;

  f32x4 acc[4][4] = {};

  const int srow[4] = { (0 * 256 + tid) >> 3, (1 * 256 + tid) >> 3,
                        (2 * 256 + tid) >> 3, (3 * 256 + tid) >> 3 };
  int scol[4];
#pragma unroll
  for (int sw = 0; sw < 4; sw++) {
    int s = sw * 256 + tid;
    scol[sw] = (s & 7) ^ (srow[sw] & 7);
  }

  for (int k0 = 0; k0 < 1024; k0 += 64) {
    __syncthreads();
#pragma unroll
    for (int sw = 0; sw < 4; sw++) {
      unsigned short* ldsA = &Al[(sw * 256 + wid * 64) * 8];  // wave-uniform base
      unsigned short* ldsB = &Bl[(sw * 256 + wid * 64) * 8];
      gload16(xb + (size_t)(m0 + srow[sw]) * 1024 + k0 + scol[sw] * 8, ldsA);
      gload16(wt + (size_t)(n0 + srow[sw]) * 1024 + k0 + scol[sw] * 8, ldsB);
    }
    __syncthreads();

#pragma unroll
    for (int ks = 0; ks < 2; ks++) {
      bf16x8 af[4], bfr[4];
#pragma unroll
      for (int mt = 0; mt < 4; mt++) {
        int row = wm + mt * 16 + l15;
        int c = (ks * 4 + g) ^ (row & 7);
        af[mt] = *(const bf16x8*)&Al[(row * 8 + c) * 8];
      }
#pragma unroll
      for (int nt = 0; nt < 4; nt++) {
        int row = wn + nt * 16 + l15;
        int c = (ks * 4 + g) ^ (row & 7);
        bfr[nt] = *(const bf16x8*)&Bl[(row * 8 + c) * 8];
      }
#pragma unroll
      for (int mt = 0; mt < 4; mt++)
#pragma unroll
        for (int nt = 0; nt < 4; nt++)
          acc[mt][nt] = __builtin_amdgcn_mfma_f32_16x16x32_bf16(af[mt], bfr[nt], acc[mt][nt], 0, 0, 0);
    }
  }

  const int r0 = g * 4, cc = l15;
#pragma unroll
  for (int mt = 0; mt < 4; mt++)
#pragma unroll
    for (int nt = 0; nt < 4; nt++)
#pragma unroll
      for (int r = 0; r < 4; r++) {
        int m = m0 + wm + mt * 16 + r0 + r;
        int n = n0 + wn + nt * 16 + cc;
        int b = m >> 11, t = m & 2047;
        int which = n >> 10, c = n & 1023;
        int h = c >> 6, d = c & 63;
        qkv[(size_t)which * QKV1 + ((size_t)((b * H_ + h) * T_ + t)) * D_ + d] =
            f2bf_cvt(acc[mt][nt][r]);
      }
}

// ---------------- causal flash attention, balanced pairs, fixed-max softmax ----------------
// grid (16, B*H). Extent map (R12): t=bh>>4, u=(x+(t>>1))&15, px=(t&1)?15-u:u;
// block handles q-tiles {px, 31-px}. Per-CU iteration sum = 98 for all x.
// Merged pair pass, shared K/V fragments; S^T softmax (R11), double P buffer
// (R15), compiler-cvt pack (R16), MFMA rowsum (R17), exp2 scale (R18),
// perm-based V pack (R19).
__global__ __launch_bounds__(256, 2) void attn(const unsigned short* __restrict__ qkv,
                                               float* __restrict__ out) {
  __shared__ unsigned short Kl[64][72];
  __shared__ unsigned short Vl[64][72];         // transposed [d][k], k XOR-swizzled
  __shared__ unsigned short Pl[2][4][16][72];   // P staging [buf][wave][q][k]
  const int tid = threadIdx.x, lane = tid & 63, wq = tid >> 6;
  const int l15 = lane & 15, g = lane >> 4;
  const int bh = blockIdx.y;
  const int tt = bh >> 4;
  const int uu = ((int)blockIdx.x + (tt >> 1)) & 15;
  const int px = (tt & 1) ? (15 - uu) : uu;
  const int qta = px, qtb = 31 - px;
  const int ntiles = qtb + 1;
  const size_t base = (size_t)bh * (T_ * D_);
  const unsigned short* qp = qkv + base;
  const unsigned short* kp = qkv + (size_t)QKV1 + base;
  const unsigned short* vp = qkv + 2 * (size_t)QKV1 + base;

  // all-ones bf16 fragment for MFMA rowsum (B operand)
  bf16x8 ones;
#pragma unroll
  for (int j = 0; j < 8; j++) ones[j] = (short)0x3F80;

  // Q scaled by 0.125 * log2(e) so softmax is raw exp2 (v_exp_f32, no mul).
  bf16x8 qfa[2], qfb[2];
#define LOADQ(QF, Q0)                                                          \
  do {                                                                         \
    int qrow_ = (Q0) + wq * 16 + l15;                                          \
    _Pragma("unroll")                                                          \
    for (int kc = 0; kc < 2; kc++) {                                           \
      bf16x8 v = *(const bf16x8*)(qp + (size_t)qrow_ * 64 + kc * 32 + g * 8);  \
      _Pragma("unroll")                                                        \
      for (int j = 0; j < 8; j++) {                                            \
        unsigned int u = (unsigned int)(unsigned short)v[j] << 16;             \
        float f = __builtin_bit_cast(float, u) * 0.18033688011112042f;         \
        v[j] = (short)f2bf_cvt(f);                                             \
      }                                                                        \
      QF[kc] = v;                                                              \
    }                                                                          \
  } while (0)
  LOADQ(qfa, qta * 64);
  LOADQ(qfb, qtb * 64);

  f32x4 oa[4] = {}, ob[4] = {};
  f32x4 rsa = {}, rsb = {};          // MFMA rowsum acc: rs[r] = Σ_k P[q=g*4+r][k]

  bf16x8 kreg0, kreg1, vreg0, vreg1;
  const int krow = tid >> 3, kch = tid & 7;
  const int vpr = tid >> 3, vdch = tid & 7;
#define LOADKV(IT)                                                             \
  do {                                                                         \
    size_t k0_ = (size_t)(IT) * 64;                                            \
    kreg0 = *(const bf16x8*)(kp + (k0_ + krow) * 64 + kch * 8);                \
    kreg1 = *(const bf16x8*)(kp + (k0_ + 32 + krow) * 64 + kch * 8);           \
    vreg0 = *(const bf16x8*)(vp + (k0_ + 2 * vpr) * 64 + vdch * 8);            \
    vreg1 = *(const bf16x8*)(vp + (k0_ + 2 * vpr + 1) * 64 + vdch * 8);        \
  } while (0)

// S^T softmax: lane (q=l15, k=g*4+r per nt). Mask, exp2, cvt-pack, ONE b64 write/nt.
#define SOFTMAXT(S, PBUF, Q0, ISDIAG, K0)                                      \
  do {                                                                         \
    if (ISDIAG) {                                                              \
      _Pragma("unroll")                                                        \
      for (int nt = 0; nt < 4; nt++) {                                         \
        _Pragma("unroll")                                                      \
        for (int r = 0; r < 4; r++) {                                          \
          int kg_ = (K0) + nt * 16 + g * 4 + r;                                \
          if (kg_ > (Q0) + wq * 16 + l15) S[nt][r] = -1e30f;                   \
        }                                                                      \
      }                                                                        \
    }                                                                          \
    _Pragma("unroll")                                                          \
    for (int nt = 0; nt < 4; nt++) {                                           \
      bf16x4 pw_;                                                              \
      _Pragma("unroll")                                                        \
      for (int r = 0; r < 4; r++) {                                            \
        float p_ = __builtin_amdgcn_exp2f(S[nt][r]);                           \
        pw_[r] = (short)f2bf_cvt(p_);                                          \
      }                                                                        \
      *(bf16x4*)&Pl[PBUF][wq][l15][nt * 16 + g * 4] = pw_;                     \
    }                                                                          \
  } while (0)

  LOADKV(0);
  for (int it = 0; it < ntiles; ++it) {
    __syncthreads();
    *(bf16x8*)&Kl[krow][kch * 8] = kreg0;
    *(bf16x8*)&Kl[32 + krow][kch * 8] = kreg1;
#pragma unroll
    for (int j = 0; j < 8; j++) {
      int d = vdch * 8 + j;
      unsigned int pk = __builtin_amdgcn_perm(
          (unsigned int)(unsigned short)vreg1[j],
          (unsigned int)(unsigned short)vreg0[j], 0x05040100u);
      *(unsigned int*)&Vl[d][(2 * vpr) ^ ((d >> 3) << 3)] = pk;
    }
    if (it + 1 < ntiles) LOADKV(it + 1);
    __syncthreads();

    const bool doA = (it <= qta);

    // ---- QK^T (swapped: S^T = K x Q) for both members, sharing K fragments ----
    f32x4 sb[4], sa[4];
    __builtin_amdgcn_s_setprio(1);
#pragma unroll
    for (int nt = 0; nt < 4; nt++) {
      bf16x8 kf0 = *(const bf16x8*)&Kl[nt * 16 + l15][g * 8];
      bf16x8 kf1 = *(const bf16x8*)&Kl[nt * 16 + l15][32 + g * 8];
      f32x4 t0 = {0.f, 0.f, 0.f, 0.f};
      t0 = __builtin_amdgcn_mfma_f32_16x16x32_bf16(kf0, qfb[0], t0, 0, 0, 0);
      t0 = __builtin_amdgcn_mfma_f32_16x16x32_bf16(kf1, qfb[1], t0, 0, 0, 0);
      sb[nt] = t0;
      if (doA) {
        f32x4 t1 = {0.f, 0.f, 0.f, 0.f};
        t1 = __builtin_amdgcn_mfma_f32_16x16x32_bf16(kf0, qfa[0], t1, 0, 0, 0);
        t1 = __builtin_amdgcn_mfma_f32_16x16x32_bf16(kf1, qfa[1], t1, 0, 0, 0);
        sa[nt] = t1;
      }
    }
    __builtin_amdgcn_s_setprio(0);

    // ---- both softmaxes -> ONE wait -> read both P fragments ----
    SOFTMAXT(sb, 0, qtb * 64, it == qtb, it * 64);
    if (doA) SOFTMAXT(sa, 1, qta * 64, it == qta, it * 64);
    asm volatile("s_waitcnt lgkmcnt(0)" ::: "memory");
    bf16x8 pb0 = *(const bf16x8*)&Pl[0][wq][l15][g * 8];
    bf16x8 pb1 = *(const bf16x8*)&Pl[0][wq][l15][32 + g * 8];
    bf16x8 pa0, pa1;
    if (doA) {
      pa0 = *(const bf16x8*)&Pl[1][wq][l15][g * 8];
      pa1 = *(const bf16x8*)&Pl[1][wq][l15][32 + g * 8];
    }

    // ---- PV + MFMA rowsum for both pair members, sharing the V fragments ----
    __builtin_amdgcn_s_setprio(1);
    rsb = __builtin_amdgcn_mfma_f32_16x16x32_bf16(pb0, ones, rsb, 0, 0, 0);
    rsb = __builtin_amdgcn_mfma_f32_16x16x32_bf16(pb1, ones, rsb, 0, 0, 0);
    if (doA) {
      rsa = __builtin_amdgcn_mfma_f32_16x16x32_bf16(pa0, ones, rsa, 0, 0, 0);
      rsa = __builtin_amdgcn_mfma_f32_16x16x32_bf16(pa1, ones, rsa, 0, 0, 0);
    }
#pragma unroll
    for (int dt = 0; dt < 4; dt++) {
      int d_ = dt * 16 + l15;
      int sw_ = (d_ >> 3) << 3;
      bf16x8 vf0 = *(const bf16x8*)&Vl[d_][(g * 8) ^ sw_];
      bf16x8 vf1 = *(const bf16x8*)&Vl[d_][(32 + g * 8) ^ sw_];
      ob[dt] = __builtin_amdgcn_mfma_f32_16x16x32_bf16(pb0, vf0, ob[dt], 0, 0, 0);
      ob[dt] = __builtin_amdgcn_mfma_f32_16x16x32_bf16(pb1, vf1, ob[dt], 0, 0, 0);
      if (doA) {
        oa[dt] = __builtin_amdgcn_mfma_f32_16x16x32_bf16(pa0, vf0, oa[dt], 0, 0, 0);
        oa[dt] = __builtin_amdgcn_mfma_f32_16x16x32_bf16(pa1, vf1, oa[dt], 0, 0, 0);
      }
    }
    __builtin_amdgcn_s_setprio(0);
  }

  // ---- epilogue: lane's rs[r] IS the rowsum for q=g*4+r — no reduction ----
  const int b = bh >> 4, h = bh & 15;
#define EPILOG(OACC, RSV, Q0)                                                  \
  do {                                                                         \
    _Pragma("unroll")                                                          \
    for (int r = 0; r < 4; r++) {                                              \
      float inv_ = 1.0f / RSV[r];                                              \
      int qg_ = (Q0) + wq * 16 + g * 4 + r;                                    \
      _Pragma("unroll")                                                        \
      for (int dt = 0; dt < 4; dt++)                                           \
        out[((size_t)(b * T_ + qg_)) * C_ + h * 64 + dt * 16 + l15] =          \
            OACC[dt][r] * inv_;                                                \
    }                                                                          \
  } while (0)
  EPILOG(ob, rsb, qtb * 64);
  EPILOG(oa, rsa, qta * 64);
}

extern "C" void kernel_launch(void* const* d_in, const int* in_sizes, int n_in,
                              void* d_out, int out_size, void* d_ws, size_t ws_size,
                              hipStream_t stream) {
  const float* x = (const float*)d_in[0];
  const float* w = (const float*)d_in[1];
  float* out = (float*)d_out;
  unsigned short* wt  = (unsigned short*)d_ws;            // 3072*1024 bf16 = 6 MB
  unsigned short* qkv = wt + (size_t)3072 * 1024;         // 3 * 8.4M bf16 = 48 MB
  // xb scratch lives in d_out (32 MB f32); attn fully overwrites it afterwards.
  unsigned short* xb  = (unsigned short*)d_out;           // 8192*1024 bf16 = 16 MB

  prep       <<<5120, 256, 0, stream>>>(x, xb, w, wt);
  qkv_gemm   <<<dim3(24, 64), 256, 0, stream>>>(xb, wt, qkv);
  attn       <<<dim3(16, 64), 256, 0, stream>>>(qkv, out);
}

// Round 20
// 137.410 us; speedup vs baseline: 1.0557x; 1.0557x over previous
//
#include <hip/hip_runtime.h>

// Problem: B=4, T=2048, C=1024, H=16, D=64.  x:[B,T,C] f32, w:[C,3C] f32.
// Plan: fused prep (x->bf16, w->w^T bf16) ; m97-style MFMA GEMM -> qkv ;
//       flash attention (causal, fixed-max softmax) -> out f32 [B,T,C].
// R11: swapped QK^T -> S^T, b64 P staging. R12: per-CU extent map + fused prep.
// R15: double P buffer. R16: compiler-cvt P pack (VALU 40->34.5, -6us).
// R17: MFMA rowsum vs all-ones fragment (VALU 34.5->31.9, epilogue reduction
//      gone). VALU chain repeatedly confirmed as attn's critical path.
// R18: fold log2(e) into Q scale (0.125*1.442695 = 0.18033688) and use
//      __builtin_amdgcn_exp2f (raw v_exp_f32): deletes the v_mul inside each
//      __expf. BEST MEASURED: 137.5 us total, attn 72.4 us.
// R19 (REVERTED): gemm-epilogue f2bf_cvt (scalar stores can't pair -> worse)
//      and V-pack v_perm (neutral-negative). Back to exact R18 source.

#define B_ 4
#define T_ 2048
#define C_ 1024
#define H_ 16
#define D_ 64
#define QKV1 (B_*H_*T_*D_)   // 8,388,608 elements per q/k/v

typedef __attribute__((ext_vector_type(4))) float  f32x4;
typedef __attribute__((ext_vector_type(8))) short  bf16x8;
typedef __attribute__((ext_vector_type(4))) short  bf16x4;

__device__ inline unsigned short f2bf(float f) {
  unsigned int u = __builtin_bit_cast(unsigned int, f);
  u += 0x7FFFu + ((u >> 16) & 1u);          // RNE
  return (unsigned short)(u >> 16);
}

// compiler-visible f32->bf16 cast: lowers to v_cvt_pk_bf16_f32 when paired
__device__ inline unsigned short f2bf_cvt(float f) {
  __bf16 h = (__bf16)f;
  return __builtin_bit_cast(unsigned short, h);
}

__device__ inline void gload16(const unsigned short* g, unsigned short* l) {
  __builtin_amdgcn_global_load_lds(
      (const __attribute__((address_space(1))) void*)g,
      (__attribute__((address_space(3))) void*)l, 16, 0, 0);
}

// ---------------- fused prep: x->bf16 (blocks 0..2047), w->w^T bf16 (2048..5119) ----
__global__ __launch_bounds__(256) void prep(const float* __restrict__ x,
                                            unsigned short* __restrict__ xb,
                                            const float* __restrict__ w,
                                            unsigned short* __restrict__ wt) {
  if (blockIdx.x < 2048) {
    size_t i = ((size_t)blockIdx.x * 256 + threadIdx.x) * 16;
    f32x4 a = *(const f32x4*)(x + i);
    f32x4 b = *(const f32x4*)(x + i + 4);
    f32x4 c = *(const f32x4*)(x + i + 8);
    f32x4 d = *(const f32x4*)(x + i + 12);
    bf16x8 o0, o1;
#pragma unroll
    for (int j = 0; j < 4; j++) {
      o0[j]     = (short)f2bf(a[j]);
      o0[j + 4] = (short)f2bf(b[j]);
      o1[j]     = (short)f2bf(c[j]);
      o1[j + 4] = (short)f2bf(d[j]);
    }
    *(bf16x8*)(xb + i) = o0;
    *(bf16x8*)(xb + i + 8) = o1;
  } else {
    __shared__ float tile[32][33];
    const int bid = blockIdx.x - 2048;
    const int tx = threadIdx.x & 31, ty = threadIdx.x >> 5;   // 32 x 8
    const int n0 = (bid % 96) * 32, k0 = (bid / 96) * 32;
#pragma unroll
    for (int j = 0; j < 4; j++) {
      int k = ty + j * 8;
      tile[k][tx] = w[(size_t)(k0 + k) * 3072 + n0 + tx];
    }
    __syncthreads();
#pragma unroll
    for (int j = 0; j < 4; j++) {
      int n = ty + j * 8;
      wt[(size_t)(n0 + n) * 1024 + k0 + tx] = f2bf(tile[tx][n]);
    }
  }
}

// ---------------- QKV GEMM: [8192,1024]bf16 x [1024,3072]bf16 -> bf16 qkv ----------------
// BM=BN=128, BK=64, 256 threads (4 waves 2x2, wave tile 64x64), 16x16x32 MFMA.
__global__ __launch_bounds__(256) void qkv_gemm(const unsigned short* __restrict__ xb,
                                                const unsigned short* __restrict__ wt,
                                                unsigned short* __restrict__ qkv) {
  __shared__ unsigned short Al[128 * 64];   // 16 KB
  __shared__ unsigned short Bl[128 * 64];   // 16 KB
  const int tid = threadIdx.x;
  const int lane = tid & 63, wid = tid >> 6;
  const int l15 = lane & 15, g = lane >> 4;
  const int m0 = blockIdx.y * 128, n0 = blockIdx.x * 128;
  const int wm = (wid >> 1) * 64, wn = (wid & 1) * 64;

  f32x4 acc[4][4] = {};

  const int srow[4] = { (0 * 256 + tid) >> 3, (1 * 256 + tid) >> 3,
                        (2 * 256 + tid) >> 3, (3 * 256 + tid) >> 3 };
  int scol[4];
#pragma unroll
  for (int sw = 0; sw < 4; sw++) {
    int s = sw * 256 + tid;
    scol[sw] = (s & 7) ^ (srow[sw] & 7);
  }

  for (int k0 = 0; k0 < 1024; k0 += 64) {
    __syncthreads();
#pragma unroll
    for (int sw = 0; sw < 4; sw++) {
      unsigned short* ldsA = &Al[(sw * 256 + wid * 64) * 8];  // wave-uniform base
      unsigned short* ldsB = &Bl[(sw * 256 + wid * 64) * 8];
      gload16(xb + (size_t)(m0 + srow[sw]) * 1024 + k0 + scol[sw] * 8, ldsA);
      gload16(wt + (size_t)(n0 + srow[sw]) * 1024 + k0 + scol[sw] * 8, ldsB);
    }
    __syncthreads();

#pragma unroll
    for (int ks = 0; ks < 2; ks++) {
      bf16x8 af[4], bfr[4];
#pragma unroll
      for (int mt = 0; mt < 4; mt++) {
        int row = wm + mt * 16 + l15;
        int c = (ks * 4 + g) ^ (row & 7);
        af[mt] = *(const bf16x8*)&Al[(row * 8 + c) * 8];
      }
#pragma unroll
      for (int nt = 0; nt < 4; nt++) {
        int row = wn + nt * 16 + l15;
        int c = (ks * 4 + g) ^ (row & 7);
        bfr[nt] = *(const bf16x8*)&Bl[(row * 8 + c) * 8];
      }
#pragma unroll
      for (int mt = 0; mt < 4; mt++)
#pragma unroll
        for (int nt = 0; nt < 4; nt++)
          acc[mt][nt] = __builtin_amdgcn_mfma_f32_16x16x32_bf16(af[mt], bfr[nt], acc[mt][nt], 0, 0, 0);
    }
  }

  const int r0 = g * 4, cc = l15;
#pragma unroll
  for (int mt = 0; mt < 4; mt++)
#pragma unroll
    for (int nt = 0; nt < 4; nt++)
#pragma unroll
      for (int r = 0; r < 4; r++) {
        int m = m0 + wm + mt * 16 + r0 + r;
        int n = n0 + wn + nt * 16 + cc;
        int b = m >> 11, t = m & 2047;
        int which = n >> 10, c = n & 1023;
        int h = c >> 6, d = c & 63;
        qkv[(size_t)which * QKV1 + ((size_t)((b * H_ + h) * T_ + t)) * D_ + d] =
            f2bf(acc[mt][nt][r]);
      }
}

// ---------------- causal flash attention, balanced pairs, fixed-max softmax ----------------
// grid (16, B*H). Extent map (R12): t=bh>>4, u=(x+(t>>1))&15, px=(t&1)?15-u:u;
// block handles q-tiles {px, 31-px}. Per-CU iteration sum = 98 for all x.
// Merged pair pass, shared K/V fragments; S^T softmax (R11), double P buffer
// (R15), compiler-cvt pack (R16), MFMA rowsum (R17), exp2-folded scale (R18).
__global__ __launch_bounds__(256, 2) void attn(const unsigned short* __restrict__ qkv,
                                               float* __restrict__ out) {
  __shared__ unsigned short Kl[64][72];
  __shared__ unsigned short Vl[64][72];         // transposed [d][k], k XOR-swizzled
  __shared__ unsigned short Pl[2][4][16][72];   // P staging [buf][wave][q][k]
  const int tid = threadIdx.x, lane = tid & 63, wq = tid >> 6;
  const int l15 = lane & 15, g = lane >> 4;
  const int bh = blockIdx.y;
  const int tt = bh >> 4;
  const int uu = ((int)blockIdx.x + (tt >> 1)) & 15;
  const int px = (tt & 1) ? (15 - uu) : uu;
  const int qta = px, qtb = 31 - px;
  const int ntiles = qtb + 1;
  const size_t base = (size_t)bh * (T_ * D_);
  const unsigned short* qp = qkv + base;
  const unsigned short* kp = qkv + (size_t)QKV1 + base;
  const unsigned short* vp = qkv + 2 * (size_t)QKV1 + base;

  // all-ones bf16 fragment for MFMA rowsum (B operand)
  bf16x8 ones;
#pragma unroll
  for (int j = 0; j < 8; j++) ones[j] = (short)0x3F80;

  // Q scaled by 0.125 * log2(e) so softmax is raw exp2 (v_exp_f32, no mul).
  bf16x8 qfa[2], qfb[2];
#define LOADQ(QF, Q0)                                                          \
  do {                                                                         \
    int qrow_ = (Q0) + wq * 16 + l15;                                          \
    _Pragma("unroll")                                                          \
    for (int kc = 0; kc < 2; kc++) {                                           \
      bf16x8 v = *(const bf16x8*)(qp + (size_t)qrow_ * 64 + kc * 32 + g * 8);  \
      _Pragma("unroll")                                                        \
      for (int j = 0; j < 8; j++) {                                            \
        unsigned int u = (unsigned int)(unsigned short)v[j] << 16;             \
        float f = __builtin_bit_cast(float, u) * 0.18033688011112042f;         \
        v[j] = (short)f2bf_cvt(f);                                             \
      }                                                                        \
      QF[kc] = v;                                                              \
    }                                                                          \
  } while (0)
  LOADQ(qfa, qta * 64);
  LOADQ(qfb, qtb * 64);

  f32x4 oa[4] = {}, ob[4] = {};
  f32x4 rsa = {}, rsb = {};          // MFMA rowsum acc: rs[r] = Σ_k P[q=g*4+r][k]

  bf16x8 kreg0, kreg1, vreg0, vreg1;
  const int krow = tid >> 3, kch = tid & 7;
  const int vpr = tid >> 3, vdch = tid & 7;
#define LOADKV(IT)                                                             \
  do {                                                                         \
    size_t k0_ = (size_t)(IT) * 64;                                            \
    kreg0 = *(const bf16x8*)(kp + (k0_ + krow) * 64 + kch * 8);                \
    kreg1 = *(const bf16x8*)(kp + (k0_ + 32 + krow) * 64 + kch * 8);           \
    vreg0 = *(const bf16x8*)(vp + (k0_ + 2 * vpr) * 64 + vdch * 8);            \
    vreg1 = *(const bf16x8*)(vp + (k0_ + 2 * vpr + 1) * 64 + vdch * 8);        \
  } while (0)

// S^T softmax: lane (q=l15, k=g*4+r per nt). Mask, exp2, cvt-pack, ONE b64 write/nt.
#define SOFTMAXT(S, PBUF, Q0, ISDIAG, K0)                                      \
  do {                                                                         \
    if (ISDIAG) {                                                              \
      _Pragma("unroll")                                                        \
      for (int nt = 0; nt < 4; nt++) {                                         \
        _Pragma("unroll")                                                      \
        for (int r = 0; r < 4; r++) {                                          \
          int kg_ = (K0) + nt * 16 + g * 4 + r;                                \
          if (kg_ > (Q0) + wq * 16 + l15) S[nt][r] = -1e30f;                   \
        }                                                                      \
      }                                                                        \
    }                                                                          \
    _Pragma("unroll")                                                          \
    for (int nt = 0; nt < 4; nt++) {                                           \
      bf16x4 pw_;                                                              \
      _Pragma("unroll")                                                        \
      for (int r = 0; r < 4; r++) {                                            \
        float p_ = __builtin_amdgcn_exp2f(S[nt][r]);                           \
        pw_[r] = (short)f2bf_cvt(p_);                                          \
      }                                                                        \
      *(bf16x4*)&Pl[PBUF][wq][l15][nt * 16 + g * 4] = pw_;                     \
    }                                                                          \
  } while (0)

  LOADKV(0);
  for (int it = 0; it < ntiles; ++it) {
    __syncthreads();
    *(bf16x8*)&Kl[krow][kch * 8] = kreg0;
    *(bf16x8*)&Kl[32 + krow][kch * 8] = kreg1;
#pragma unroll
    for (int j = 0; j < 8; j++) {
      int d = vdch * 8 + j;
      unsigned int pk = ((unsigned int)(unsigned short)vreg1[j] << 16) |
                        (unsigned int)(unsigned short)vreg0[j];
      *(unsigned int*)&Vl[d][(2 * vpr) ^ ((d >> 3) << 3)] = pk;
    }
    if (it + 1 < ntiles) LOADKV(it + 1);
    __syncthreads();

    const bool doA = (it <= qta);

    // ---- QK^T (swapped: S^T = K x Q) for both members, sharing K fragments ----
    f32x4 sb[4], sa[4];
    __builtin_amdgcn_s_setprio(1);
#pragma unroll
    for (int nt = 0; nt < 4; nt++) {
      bf16x8 kf0 = *(const bf16x8*)&Kl[nt * 16 + l15][g * 8];
      bf16x8 kf1 = *(const bf16x8*)&Kl[nt * 16 + l15][32 + g * 8];
      f32x4 t0 = {0.f, 0.f, 0.f, 0.f};
      t0 = __builtin_amdgcn_mfma_f32_16x16x32_bf16(kf0, qfb[0], t0, 0, 0, 0);
      t0 = __builtin_amdgcn_mfma_f32_16x16x32_bf16(kf1, qfb[1], t0, 0, 0, 0);
      sb[nt] = t0;
      if (doA) {
        f32x4 t1 = {0.f, 0.f, 0.f, 0.f};
        t1 = __builtin_amdgcn_mfma_f32_16x16x32_bf16(kf0, qfa[0], t1, 0, 0, 0);
        t1 = __builtin_amdgcn_mfma_f32_16x16x32_bf16(kf1, qfa[1], t1, 0, 0, 0);
        sa[nt] = t1;
      }
    }
    __builtin_amdgcn_s_setprio(0);

    // ---- both softmaxes -> ONE wait -> read both P fragments ----
    SOFTMAXT(sb, 0, qtb * 64, it == qtb, it * 64);
    if (doA) SOFTMAXT(sa, 1, qta * 64, it == qta, it * 64);
    asm volatile("s_waitcnt lgkmcnt(0)" ::: "memory");
    bf16x8 pb0 = *(const bf16x8*)&Pl[0][wq][l15][g * 8];
    bf16x8 pb1 = *(const bf16x8*)&Pl[0][wq][l15][32 + g * 8];
    bf16x8 pa0, pa1;
    if (doA) {
      pa0 = *(const bf16x8*)&Pl[1][wq][l15][g * 8];
      pa1 = *(const bf16x8*)&Pl[1][wq][l15][32 + g * 8];
    }

    // ---- PV + MFMA rowsum for both pair members, sharing the V fragments ----
    __builtin_amdgcn_s_setprio(1);
    rsb = __builtin_amdgcn_mfma_f32_16x16x32_bf16(pb0, ones, rsb, 0, 0, 0);
    rsb = __builtin_amdgcn_mfma_f32_16x16x32_bf16(pb1, ones, rsb, 0, 0, 0);
    if (doA) {
      rsa = __builtin_amdgcn_mfma_f32_16x16x32_bf16(pa0, ones, rsa, 0, 0, 0);
      rsa = __builtin_amdgcn_mfma_f32_16x16x32_bf16(pa1, ones, rsa, 0, 0, 0);
    }
#pragma unroll
    for (int dt = 0; dt < 4; dt++) {
      int d_ = dt * 16 + l15;
      int sw_ = (d_ >> 3) << 3;
      bf16x8 vf0 = *(const bf16x8*)&Vl[d_][(g * 8) ^ sw_];
      bf16x8 vf1 = *(const bf16x8*)&Vl[d_][(32 + g * 8) ^ sw_];
      ob[dt] = __builtin_amdgcn_mfma_f32_16x16x32_bf16(pb0, vf0, ob[dt], 0, 0, 0);
      ob[dt] = __builtin_amdgcn_mfma_f32_16x16x32_bf16(pb1, vf1, ob[dt], 0, 0, 0);
      if (doA) {
        oa[dt] = __builtin_amdgcn_mfma_f32_16x16x32_bf16(pa0, vf0, oa[dt], 0, 0, 0);
        oa[dt] = __builtin_amdgcn_mfma_f32_16x16x32_bf16(pa1, vf1, oa[dt], 0, 0, 0);
      }
    }
    __builtin_amdgcn_s_setprio(0);
  }

  // ---- epilogue: lane's rs[r] IS the rowsum for q=g*4+r — no reduction ----
  const int b = bh >> 4, h = bh & 15;
#define EPILOG(OACC, RSV, Q0)                                                  \
  do {                                                                         \
    _Pragma("unroll")                                                          \
    for (int r = 0; r < 4; r++) {                                              \
      float inv_ = 1.0f / RSV[r];                                              \
      int qg_ = (Q0) + wq * 16 + g * 4 + r;                                    \
      _Pragma("unroll")                                                        \
      for (int dt = 0; dt < 4; dt++)                                           \
        out[((size_t)(b * T_ + qg_)) * C_ + h * 64 + dt * 16 + l15] =          \
            OACC[dt][r] * inv_;                                                \
    }                                                                          \
  } while (0)
  EPILOG(ob, rsb, qtb * 64);
  EPILOG(oa, rsa, qta * 64);
}

extern "C" void kernel_launch(void* const* d_in, const int* in_sizes, int n_in,
                              void* d_out, int out_size, void* d_ws, size_t ws_size,
                              hipStream_t stream) {
  const float* x = (const float*)d_in[0];
  const float* w = (const float*)d_in[1];
  float* out = (float*)d_out;
  unsigned short* wt  = (unsigned short*)d_ws;            // 3072*1024 bf16 = 6 MB
  unsigned short* qkv = wt + (size_t)3072 * 1024;         // 3 * 8.4M bf16 = 48 MB
  // xb scratch lives in d_out (32 MB f32); attn fully overwrites it afterwards.
  unsigned short* xb  = (unsigned short*)d_out;           // 8192*1024 bf16 = 16 MB

  prep       <<<5120, 256, 0, stream>>>(x, xb, w, wt);
  qkv_gemm   <<<dim3(24, 64), 256, 0, stream>>>(xb, wt, qkv);
  attn       <<<dim3(16, 64), 256, 0, stream>>>(qkv, out);
}